// Round 1
// baseline (134.129 us; speedup 1.0000x reference)
//
#include <hip/hip_runtime.h>

typedef __attribute__((ext_vector_type(8))) short short8;
typedef __attribute__((ext_vector_type(4))) float f32x4;

#define DEVI __device__ __forceinline__

DEVI unsigned short f2bf(float f) {
    union { float f; unsigned u; } v; v.f = f;
    unsigned r = v.u + 0x7FFFu + ((v.u >> 16) & 1u);   // RNE
    return (unsigned short)(r >> 16);
}

// ---------------- 4-qubit circuit, one sample per thread ----------------
// flat state index s: wire w <-> bit (3-w).  RX init, 3 layers of (Rot x4, CNOT chain)
DEVI void run_circuit(const float lat[4], const float* __restrict__ qw, float out4[4])
{
    float cw[4], sw[4];
#pragma unroll
    for (int w = 0; w < 4; ++w) sincosf(0.5f * lat[w], &sw[w], &cw[w]);

    float sr[16], si[16];
#pragma unroll
    for (int s = 0; s < 16; ++s) {
        float mag = 1.f; int p = 0;
#pragma unroll
        for (int w = 0; w < 4; ++w) {
            int b = (s >> (3 - w)) & 1;
            mag *= b ? sw[w] : cw[w];
            p += b;
        }
        p &= 3;   // amp = mag * (-i)^p
        sr[s] = (p == 0) ? mag : ((p == 2) ? -mag : 0.f);
        si[s] = (p == 1) ? -mag : ((p == 3) ? mag : 0.f);
    }

#pragma unroll
    for (int L = 0; L < 3; ++L) {
#pragma unroll
        for (int q = 0; q < 4; ++q) {
            const float* g = qw + (L * 4 + q) * 3;
            float phi = g[0], th = g[1], om = g[2];
            float ct, st;
            sincosf(0.5f * th, &st, &ct);
            float ap = 0.5f * (phi + om), am = 0.5f * (phi - om);
            float cap, sap, cam, sam;
            sincosf(ap, &sap, &cap);
            sincosf(am, &sam, &cam);
            // Rot = RZ(om) RY(th) RZ(phi)
            float u00r =  ct * cap, u00i = -ct * sap;
            float u01r = -st * cam, u01i = -st * sam;
            float u10r =  st * cam, u10i = -st * sam;
            float u11r =  ct * cap, u11i =  ct * sap;
            int bm = 8 >> q;
#pragma unroll
            for (int i = 0; i < 16; ++i) {
                if (i & bm) continue;
                int j = i | bm;
                float ar = sr[i], ai = si[i], br = sr[j], bi = si[j];
                sr[i] = u00r*ar - u00i*ai + u01r*br - u01i*bi;
                si[i] = u00r*ai + u00i*ar + u01r*bi + u01i*br;
                sr[j] = u10r*ar - u10i*ai + u11r*br - u11i*bi;
                si[j] = u10r*ai + u10i*ar + u11r*bi + u11i*br;
            }
        }
#pragma unroll
        for (int q = 0; q < 3; ++q) {     // CNOT(q, q+1)
            int cm = 8 >> q, tm = 8 >> (q + 1);
#pragma unroll
            for (int i = 0; i < 16; ++i) {
                if ((i & cm) && !(i & tm)) {
                    int j = i | tm;
                    float tr = sr[i]; sr[i] = sr[j]; sr[j] = tr;
                    float ti = si[i]; si[i] = si[j]; si[j] = ti;
                }
            }
        }
    }
#pragma unroll
    for (int q = 0; q < 4; ++q) {
        int bm = 8 >> q;
        float e = 0.f;
#pragma unroll
        for (int i = 0; i < 16; ++i) {
            float p = sr[i]*sr[i] + si[i]*si[i];
            e += (i & bm) ? -p : p;
        }
        out4[q] = e;
    }
}

// ---------------- prep: weights -> bf16 [N][K] in ws ----------------
// elem offsets in ws (ushort): w0eT=0 (128x2048), w1eT=262144 (64x128),
// w1dT=270336 (128x64), w2dT=278528 (2048x128). refined f32 @ byte 1081344.
__global__ void prep_kernel(const float* __restrict__ ew0, const float* __restrict__ ew1,
                            const float* __restrict__ dw1, const float* __restrict__ dw2,
                            unsigned short* __restrict__ wsb)
{
    int i = blockIdx.x * 256 + threadIdx.x;
    if (i < 262144) {                       // w0eT[n][k] = enc_w0[k][n], k<2048,n<128
        int n = i >> 11, k = i & 2047;
        wsb[i] = f2bf(ew0[k * 128 + n]);
    } else if (i < 270336) {                // w1eT[n][k] = enc_w1[k][n], k<128,n<64
        int t = i - 262144; int n = t >> 7, k = t & 127;
        wsb[i] = f2bf(ew1[k * 64 + n]);
    } else if (i < 278528) {                // w1dT[n][k] = dec_w1[k][n], k<64,n<128
        int t = i - 270336; int n = t >> 6, k = t & 63;
        wsb[i] = f2bf(dw1[k * 128 + n]);
    } else if (i < 540672) {                // w2dT[n][k] = dec_w2[k][n], k<128,n<2048
        int t = i - 278528; int n = t >> 7, k = t & 127;
        wsb[i] = f2bf(dw2[k * 2048 + n]);
    }
}

// ---------------- encoder + circuit ----------------
// per block: 64 rows. GEMM1 (K=2048,N=128) dbuf MFMA; GEMM2 (K=128,N=64) MFMA;
// latent (K=64,N=4) VALU; circuit; write refined.
__launch_bounds__(256, 1)
__global__ void enc_kernel(const float* __restrict__ x,
                           const unsigned short* __restrict__ w0T,
                           const unsigned short* __restrict__ w1T,
                           const float* __restrict__ b0g,
                           const float* __restrict__ b1g,
                           const float* __restrict__ w2g,
                           const float* __restrict__ b2g,
                           const float* __restrict__ qw,
                           float* __restrict__ refined)
{
    __shared__ __align__(16) char smem[50432];
    char* const Abuf0 = smem;                    // [64][64] bf16, 128B rows, swz
    char* const Abuf1 = smem + 8192;
    char* const Bbuf0 = smem + 16384;            // [128][64] bf16
    char* const Bbuf1 = smem + 32768;
    char* const H1 = smem;                       // phase2: [64][128] bf16, 256B rows
    char* const W1 = smem + 16384;               // [64][128] bf16
    float* const H2 = (float*)(smem + 32768);    // [64][65] f32
    float* const W2C = (float*)(smem + 49408);   // [64][4] f32

    const int tid = threadIdx.x;
    const int lane = tid & 63;
    const int wv = tid >> 6;
    const int wm = wv >> 1, wn = wv & 1;
    const int l16 = lane & 15, lq = lane >> 4;
    const int m0 = blockIdx.x * 64;

    const int ar = tid >> 4;       // A stage: row base, +16j
    const int ac4 = tid & 15;      // float4 index in row
    const int bn = tid >> 3;       // B stage: row base, +32j
    const int bs = tid & 7;        // 16B slot

    const float* xg = x + m0 * 2048;

    // stage enc_w2[:, :4] once (tiny)
    W2C[tid] = w2g[(tid >> 2) * 32 + (tid & 3)];

    f32x4 acc[2][4];
#pragma unroll
    for (int a = 0; a < 2; ++a)
#pragma unroll
        for (int b = 0; b < 4; ++b) acc[a][b] = (f32x4)(0.f);

    float4 aL[4];
    uint4 bL[4];

    auto issue_loads = [&](int k0) {
#pragma unroll
        for (int j = 0; j < 4; ++j)
            aL[j] = *(const float4*)(xg + (ar + 16 * j) * 2048 + k0 + ac4 * 4);
#pragma unroll
        for (int j = 0; j < 4; ++j)
            bL[j] = *(const uint4*)(w0T + (bn + 32 * j) * 2048 + k0 + bs * 8);
    };
    auto write_lds = [&](int buf) {
        char* A = buf ? Abuf1 : Abuf0;
        char* B = buf ? Bbuf1 : Bbuf0;
#pragma unroll
        for (int j = 0; j < 4; ++j) {
            int r = ar + 16 * j;
            unsigned p0 = (unsigned)f2bf(aL[j].x) | ((unsigned)f2bf(aL[j].y) << 16);
            unsigned p1 = (unsigned)f2bf(aL[j].z) | ((unsigned)f2bf(aL[j].w) << 16);
            unsigned long long pk = (unsigned long long)p0 | ((unsigned long long)p1 << 32);
            *(unsigned long long*)(A + r * 128 + ((((ac4 >> 1) ^ (r & 7)) << 4) | ((ac4 & 1) << 3))) = pk;
        }
#pragma unroll
        for (int j = 0; j < 4; ++j) {
            int n = bn + 32 * j;
            *(uint4*)(B + n * 128 + ((bs ^ (n & 7)) << 4)) = bL[j];
        }
    };
    auto compute_tile = [&](int buf) {
        char* A = buf ? Abuf1 : Abuf0;
        char* B = buf ? Bbuf1 : Bbuf0;
#pragma unroll
        for (int kk = 0; kk < 2; ++kk) {
            short8 aF[2], bF[4];
#pragma unroll
            for (int fm = 0; fm < 2; ++fm) {
                int row = wm * 32 + fm * 16 + l16;
                aF[fm] = *(const short8*)(A + row * 128 + (((kk * 4 + lq) ^ (row & 7)) << 4));
            }
#pragma unroll
            for (int fn = 0; fn < 4; ++fn) {
                int n = wn * 64 + fn * 16 + l16;
                bF[fn] = *(const short8*)(B + n * 128 + (((kk * 4 + lq) ^ (n & 7)) << 4));
            }
#pragma unroll
            for (int fm = 0; fm < 2; ++fm)
#pragma unroll
                for (int fn = 0; fn < 4; ++fn)
                    acc[fm][fn] = __builtin_amdgcn_mfma_f32_16x16x32_bf16(aF[fm], bF[fn], acc[fm][fn], 0, 0, 0);
        }
    };

    issue_loads(0);
    write_lds(0);
    __syncthreads();
#pragma unroll 2
    for (int it = 0; it < 32; ++it) {
        if (it < 31) issue_loads((it + 1) * 64);
        compute_tile(it & 1);
        if (it < 31) {
            write_lds((it + 1) & 1);
            __syncthreads();
        }
    }
    __syncthreads();   // GEMM1 reads done; LDS regions about to be reused

    // stage w1eT -> regs (L2-hot), write after epilogue1
    uint4 wL[4];
#pragma unroll
    for (int j = 0; j < 4; ++j) {
        int u = tid + 256 * j, n = u >> 4, s = u & 15;
        wL[j] = *(const uint4*)(w1T + n * 128 + s * 8);
    }
    float b0v[4];
#pragma unroll
    for (int fn = 0; fn < 4; ++fn) b0v[fn] = b0g[wn * 64 + fn * 16 + l16];
    // epilogue1: h1 = relu(acc + b0) -> H1 (A-layout, swz)
#pragma unroll
    for (int fm = 0; fm < 2; ++fm)
#pragma unroll
        for (int fn = 0; fn < 4; ++fn)
#pragma unroll
            for (int r = 0; r < 4; ++r) {
                int row = wm * 32 + fm * 16 + lq * 4 + r;
                int col = wn * 64 + fn * 16 + l16;
                float v = fmaxf(acc[fm][fn][r] + b0v[fn], 0.f);
                *(unsigned short*)(H1 + row * 256 + ((((col >> 3) ^ (row & 7)) << 4) | ((col & 7) << 1))) = f2bf(v);
            }
#pragma unroll
    for (int j = 0; j < 4; ++j) {
        int u = tid + 256 * j, n = u >> 4, s = u & 15;
        *(uint4*)(W1 + n * 256 + ((s ^ (n & 7)) << 4)) = wL[j];
    }
    __syncthreads();

    // GEMM2: h2 = relu(h1 @ w1 + b1), 64x64, K=128
    f32x4 acc2[2][2];
#pragma unroll
    for (int a = 0; a < 2; ++a)
#pragma unroll
        for (int b = 0; b < 2; ++b) acc2[a][b] = (f32x4)(0.f);
#pragma unroll
    for (int kk = 0; kk < 4; ++kk) {
        short8 aF[2], bF[2];
#pragma unroll
        for (int fm = 0; fm < 2; ++fm) {
            int row = wm * 32 + fm * 16 + l16;
            aF[fm] = *(const short8*)(H1 + row * 256 + (((kk * 4 + lq) ^ (row & 7)) << 4));
        }
#pragma unroll
        for (int fn = 0; fn < 2; ++fn) {
            int n = wn * 32 + fn * 16 + l16;
            bF[fn] = *(const short8*)(W1 + n * 256 + (((kk * 4 + lq) ^ (n & 7)) << 4));
        }
#pragma unroll
        for (int fm = 0; fm < 2; ++fm)
#pragma unroll
            for (int fn = 0; fn < 2; ++fn)
                acc2[fm][fn] = __builtin_amdgcn_mfma_f32_16x16x32_bf16(aF[fm], bF[fn], acc2[fm][fn], 0, 0, 0);
    }
    float b1v[2];
#pragma unroll
    for (int fn = 0; fn < 2; ++fn) b1v[fn] = b1g[wn * 32 + fn * 16 + l16];
#pragma unroll
    for (int fm = 0; fm < 2; ++fm)
#pragma unroll
        for (int fn = 0; fn < 2; ++fn)
#pragma unroll
            for (int r = 0; r < 4; ++r) {
                int row = wm * 32 + fm * 16 + lq * 4 + r;
                int col = wn * 32 + fn * 16 + l16;
                H2[row * 65 + col] = fmaxf(acc2[fm][fn][r] + b1v[fn], 0.f);
            }
    __syncthreads();

    // latent (4 cols) + circuit, one row per thread (wave 0)
    if (tid < 64) {
        float lat[4];
#pragma unroll
        for (int j = 0; j < 4; ++j) lat[j] = b2g[j];
        const float* h2row = H2 + tid * 65;
#pragma unroll 8
        for (int k = 0; k < 64; ++k) {
            float hv = h2row[k];
#pragma unroll
            for (int j = 0; j < 4; ++j) lat[j] = fmaf(hv, W2C[k * 4 + j], lat[j]);
        }
        float o4[4];
        run_circuit(lat, qw, o4);
        *(float4*)(refined + (m0 + tid) * 4) = make_float4(o4[0], o4[1], o4[2], o4[3]);
    }
}

// ---------------- decoder ----------------
__launch_bounds__(256, 1)
__global__ void dec_kernel(const float* __restrict__ refined,
                           const float* __restrict__ w0g,   // dec_w0 [4][64] f32
                           const float* __restrict__ b0g,   // [64]
                           const unsigned short* __restrict__ w1T, // [128][64] bf16
                           const float* __restrict__ b1g,   // [128]
                           const unsigned short* __restrict__ w2T, // [2048][128] bf16
                           const float* __restrict__ b2g,   // [2048]
                           float* __restrict__ out)
{
    __shared__ __align__(16) char smem[106496];
    char* const HA  = smem;            // [64][64] bf16
    char* const W1  = smem + 8192;     // [128][64] bf16
    char* const GA  = smem + 24576;    // [64][128] bf16
    char* const W2a = smem + 40960;    // [128][128] bf16
    char* const W2b = smem + 73728;

    const int tid = threadIdx.x;
    const int lane = tid & 63;
    const int wv = tid >> 6;
    const int wm = wv >> 1, wn = wv & 1;
    const int l16 = lane & 15, lq = lane >> 4;
    const int m0 = blockIdx.x * 64;

    // stage w1dT
    uint4 w1L[4];
#pragma unroll
    for (int j = 0; j < 4; ++j)
        w1L[j] = *(const uint4*)(w1T + ((tid >> 3) + 32 * j) * 64 + (tid & 7) * 8);

    // h = relu(refined @ dec_w0 + b0), K=4 on VALU
    const int hr = tid >> 2, hc0 = (tid & 3) * 16;
    float4 rf = *(const float4*)(refined + (m0 + hr) * 4);
    unsigned short hb[16];
#pragma unroll
    for (int i = 0; i < 16; ++i) {
        int c = hc0 + i;
        float v = rf.x * w0g[c] + rf.y * w0g[64 + c] + rf.z * w0g[128 + c] + rf.w * w0g[192 + c] + b0g[c];
        hb[i] = f2bf(fmaxf(v, 0.f));
    }
#pragma unroll
    for (int half = 0; half < 2; ++half) {
        uint4 pk;
        pk.x = (unsigned)hb[half*8+0] | ((unsigned)hb[half*8+1] << 16);
        pk.y = (unsigned)hb[half*8+2] | ((unsigned)hb[half*8+3] << 16);
        pk.z = (unsigned)hb[half*8+4] | ((unsigned)hb[half*8+5] << 16);
        pk.w = (unsigned)hb[half*8+6] | ((unsigned)hb[half*8+7] << 16);
        int slot = (tid & 3) * 2 + half;
        *(uint4*)(HA + hr * 128 + ((slot ^ (hr & 7)) << 4)) = pk;
    }
#pragma unroll
    for (int j = 0; j < 4; ++j) {
        int n = (tid >> 3) + 32 * j;
        *(uint4*)(W1 + n * 128 + (((tid & 7) ^ (n & 7)) << 4)) = w1L[j];
    }
    // prefetch w2 chunk 0
    uint4 w2L[8];
    const int w2n = tid >> 4, w2s = tid & 15;
#pragma unroll
    for (int j = 0; j < 8; ++j)
        w2L[j] = *(const uint4*)(w2T + (w2n + 16 * j) * 128 + w2s * 8);
    __syncthreads();

    // GEMM2: g = relu(h @ dec_w1 + b1), 64x128, K=64
    f32x4 accg[2][4];
#pragma unroll
    for (int a = 0; a < 2; ++a)
#pragma unroll
        for (int b = 0; b < 4; ++b) accg[a][b] = (f32x4)(0.f);
#pragma unroll
    for (int kk = 0; kk < 2; ++kk) {
        short8 aF[2], bF[4];
#pragma unroll
        for (int fm = 0; fm < 2; ++fm) {
            int row = wm * 32 + fm * 16 + l16;
            aF[fm] = *(const short8*)(HA + row * 128 + (((kk * 4 + lq) ^ (row & 7)) << 4));
        }
#pragma unroll
        for (int fn = 0; fn < 4; ++fn) {
            int n = wn * 64 + fn * 16 + l16;
            bF[fn] = *(const short8*)(W1 + n * 128 + (((kk * 4 + lq) ^ (n & 7)) << 4));
        }
#pragma unroll
        for (int fm = 0; fm < 2; ++fm)
#pragma unroll
            for (int fn = 0; fn < 4; ++fn)
                accg[fm][fn] = __builtin_amdgcn_mfma_f32_16x16x32_bf16(aF[fm], bF[fn], accg[fm][fn], 0, 0, 0);
    }
    float b1v[4];
#pragma unroll
    for (int fn = 0; fn < 4; ++fn) b1v[fn] = b1g[wn * 64 + fn * 16 + l16];
#pragma unroll
    for (int fm = 0; fm < 2; ++fm)
#pragma unroll
        for (int fn = 0; fn < 4; ++fn)
#pragma unroll
            for (int r = 0; r < 4; ++r) {
                int row = wm * 32 + fm * 16 + lq * 4 + r;
                int col = wn * 64 + fn * 16 + l16;
                float v = fmaxf(accg[fm][fn][r] + b1v[fn], 0.f);
                *(unsigned short*)(GA + row * 256 + ((((col >> 3) ^ (row & 7)) << 4) | ((col & 7) << 1))) = f2bf(v);
            }
#pragma unroll
    for (int j = 0; j < 8; ++j) {
        int n = w2n + 16 * j;
        *(uint4*)(W2a + n * 256 + ((w2s ^ (n & 7)) << 4)) = w2L[j];
    }
    __syncthreads();

    // GEMM3: out = g @ dec_w2 + b2, K=128, N-chunks of 128
#pragma unroll 2
    for (int nc = 0; nc < 16; ++nc) {
        char* Wc = (nc & 1) ? W2b : W2a;
        if (nc < 15) {
#pragma unroll
            for (int j = 0; j < 8; ++j)
                w2L[j] = *(const uint4*)(w2T + ((nc + 1) * 128 + w2n + 16 * j) * 128 + w2s * 8);
        }
        f32x4 a3[2][4];
#pragma unroll
        for (int a = 0; a < 2; ++a)
#pragma unroll
            for (int b = 0; b < 4; ++b) a3[a][b] = (f32x4)(0.f);
#pragma unroll
        for (int kk = 0; kk < 4; ++kk) {
            short8 aF[2], bF[4];
#pragma unroll
            for (int fm = 0; fm < 2; ++fm) {
                int row = wm * 32 + fm * 16 + l16;
                aF[fm] = *(const short8*)(GA + row * 256 + (((kk * 4 + lq) ^ (row & 7)) << 4));
            }
#pragma unroll
            for (int fn = 0; fn < 4; ++fn) {
                int n = wn * 64 + fn * 16 + l16;
                bF[fn] = *(const short8*)(Wc + n * 256 + (((kk * 4 + lq) ^ (n & 7)) << 4));
            }
#pragma unroll
            for (int fm = 0; fm < 2; ++fm)
#pragma unroll
                for (int fn = 0; fn < 4; ++fn)
                    a3[fm][fn] = __builtin_amdgcn_mfma_f32_16x16x32_bf16(aF[fm], bF[fn], a3[fm][fn], 0, 0, 0);
        }
        int n0 = nc * 128;
        float b2v[4];
#pragma unroll
        for (int fn = 0; fn < 4; ++fn) b2v[fn] = b2g[n0 + wn * 64 + fn * 16 + l16];
#pragma unroll
        for (int fm = 0; fm < 2; ++fm)
#pragma unroll
            for (int fn = 0; fn < 4; ++fn)
#pragma unroll
                for (int r = 0; r < 4; ++r) {
                    int row = m0 + wm * 32 + fm * 16 + lq * 4 + r;
                    int col = n0 + wn * 64 + fn * 16 + l16;
                    out[row * 2048 + col] = a3[fm][fn][r] + b2v[fn];
                }
        if (nc < 15) {
            char* Wn = (nc & 1) ? W2a : W2b;
#pragma unroll
            for (int j = 0; j < 8; ++j) {
                int n = w2n + 16 * j;
                *(uint4*)(Wn + n * 256 + ((w2s ^ (n & 7)) << 4)) = w2L[j];
            }
            __syncthreads();
        }
    }
}

extern "C" void kernel_launch(void* const* d_in, const int* in_sizes, int n_in,
                              void* d_out, int out_size, void* d_ws, size_t ws_size,
                              hipStream_t stream)
{
    (void)in_sizes; (void)n_in; (void)out_size; (void)ws_size;
    const float* x      = (const float*)d_in[0];
    const float* enc_w0 = (const float*)d_in[1];
    const float* enc_b0 = (const float*)d_in[2];
    const float* enc_w1 = (const float*)d_in[3];
    const float* enc_b1 = (const float*)d_in[4];
    const float* enc_w2 = (const float*)d_in[5];
    const float* enc_b2 = (const float*)d_in[6];
    const float* qw     = (const float*)d_in[7];
    const float* dec_w0 = (const float*)d_in[8];
    const float* dec_b0 = (const float*)d_in[9];
    const float* dec_w1 = (const float*)d_in[10];
    const float* dec_b1 = (const float*)d_in[11];
    const float* dec_w2 = (const float*)d_in[12];
    const float* dec_b2 = (const float*)d_in[13];

    unsigned short* wsb = (unsigned short*)d_ws;
    float* refined = (float*)((char*)d_ws + 1081344);

    prep_kernel<<<2112, 256, 0, stream>>>(enc_w0, enc_w1, dec_w1, dec_w2, wsb);
    enc_kernel<<<256, 256, 0, stream>>>(x, wsb, wsb + 262144,
                                        enc_b0, enc_b1, enc_w2, enc_b2, qw, refined);
    dec_kernel<<<256, 256, 0, stream>>>(refined, dec_w0, dec_b0, wsb + 270336,
                                        dec_b1, wsb + 278528, dec_b2, (float*)d_out);
}